// Round 9
// baseline (448.396 us; speedup 1.0000x reference)
//
#include <hip/hip_runtime.h>

#define D 64
#define SCAN_CHUNK 1024
#define MAX_CHUNKS 128
#define BSHIFT 9                 // 512 nodes per bucket
#define BNODES (1 << BSHIFT)
#define CHUNK 8192               // edges per partition block

__device__ int g_partials[MAX_CHUNKS];

// ------------------------------------------------ exclusive scan (3 kernels)
__global__ __launch_bounds__(256) void scanA(const int* __restrict__ cnt, int n) {
    __shared__ int red[256];
    int b = blockIdx.x, t = threadIdx.x;
    int base = b * SCAN_CHUNK + t * 4;
    int s = 0;
#pragma unroll
    for (int j = 0; j < 4; ++j) {
        int i = base + j;
        if (i < n) s += cnt[i];
    }
    red[t] = s;
    __syncthreads();
    for (int off = 128; off > 0; off >>= 1) {
        if (t < off) red[t] += red[t + off];
        __syncthreads();
    }
    if (t == 0) g_partials[b] = red[0];
}

__global__ __launch_bounds__(128) void scanB(int nchunks) {
    __shared__ int sh[MAX_CHUNKS];
    int t = threadIdx.x;
    int v = (t < nchunks) ? g_partials[t] : 0;
    sh[t] = v;
    __syncthreads();
    for (int off = 1; off < MAX_CHUNKS; off <<= 1) {
        int a = (t >= off) ? sh[t - off] : 0;
        __syncthreads();
        sh[t] += a;
        __syncthreads();
    }
    if (t < nchunks) g_partials[t] = sh[t] - v;  // exclusive
}

// out-of-place: offs[i] = exclusive_prefix(cnt)[i]  (cnt preserved)
__global__ __launch_bounds__(256) void scanC(const int* __restrict__ cnt,
                                             int* __restrict__ offs, int n) {
    __shared__ int sums[256];
    int b = blockIdx.x, t = threadIdx.x;
    int base = b * SCAN_CHUNK + t * 4;
    int v[4];
    int tot = 0;
#pragma unroll
    for (int j = 0; j < 4; ++j) {
        int i = base + j;
        v[j] = (i < n) ? cnt[i] : 0;
        tot += v[j];
    }
    sums[t] = tot;
    __syncthreads();
    for (int off = 1; off < 256; off <<= 1) {
        int a = (t >= off) ? sums[t - off] : 0;
        __syncthreads();
        sums[t] += a;
        __syncthreads();
    }
    int run = sums[t] - tot + g_partials[b];
#pragma unroll
    for (int j = 0; j < 4; ++j) {
        int i = base + j;
        if (i < n) offs[i] = run;
        run += v[j];
    }
}

// ------------------------------------------------ partAB: per-(chunk,bucket) counts for dst AND src
__global__ __launch_bounds__(256) void partAB(const int* __restrict__ src,
                                              const int* __restrict__ dst,
                                              int* __restrict__ histJ,
                                              int E, int G, int NB, int HL) {
    __shared__ int hD[256], hS[256];
    int g = blockIdx.x;
    hD[threadIdx.x] = 0;
    hS[threadIdx.x] = 0;
    __syncthreads();
    int base = g * CHUNK;
    int lim = min(E - base, CHUNK);
    for (int i = threadIdx.x; i < lim; i += 256) {
        atomicAdd(&hD[dst[base + i] >> BSHIFT], 1);
        atomicAdd(&hS[src[base + i] >> BSHIFT], 1);
    }
    __syncthreads();
    if (threadIdx.x < NB) {
        histJ[threadIdx.x * G + g] = hD[threadIdx.x];
        histJ[HL + threadIdx.x * G + g] = hS[threadIdx.x];
    }
}

// ------------------------------------------------ partCJ: bucket-major reorder for both partitions (SoA)
__global__ __launch_bounds__(256) void partCJ(const int* __restrict__ src,
                                              const int* __restrict__ dst,
                                              const int* __restrict__ histJs,
                                              int* __restrict__ ebufS, int* __restrict__ ebufD,
                                              int* __restrict__ ebufK,
                                              int E, int G, int NB, int HL) {
    __shared__ int curD[256], curK[256];
    int g = blockIdx.x;
    if (threadIdx.x < NB) {
        curD[threadIdx.x] = histJs[threadIdx.x * G + g];
        curK[threadIdx.x] = histJs[HL + threadIdx.x * G + g];
    }
    __syncthreads();
    int base = g * CHUNK;
    int lim = min(E - base, CHUNK);
    for (int i = threadIdx.x; i < lim; i += 256) {
        int d = dst[base + i];
        int s = src[base + i];
        int pD = atomicAdd(&curD[d >> BSHIFT], 1);
        ebufS[pD] = s;
        ebufD[pD] = d;
        int pK = atomicAdd(&curK[s >> BSHIFT], 1) - E;  // src positions offset by E in joint scan
        ebufK[pK] = s;
    }
}

// ------------------------------------------------ partDcount: per-bucket node degrees (LDS), coalesced writes
__global__ __launch_bounds__(256) void partDcount(const int* __restrict__ ebufD,
                                                  const int* __restrict__ ebufK,
                                                  const int* __restrict__ histJs,
                                                  int* __restrict__ cnt_dst, float* __restrict__ rs_src,
                                                  int E, int G, int NB, int HL, int N) {
    __shared__ int cntD[BNODES], cntS[BNODES];
    int b = blockIdx.x;
    int nbase = b << BSHIFT;
    for (int i = threadIdx.x; i < BNODES; i += 256) { cntD[i] = 0; cntS[i] = 0; }
    __syncthreads();
    int dS = histJs[b * G];
    int dE = (b + 1 < NB) ? histJs[(b + 1) * G] : E;
    for (int p = dS + threadIdx.x; p < dE; p += 256)
        atomicAdd(&cntD[ebufD[p] - nbase], 1);
    int kS = histJs[HL + b * G] - E;
    int kE = (b + 1 < NB) ? histJs[HL + (b + 1) * G] - E : E;
    for (int p = kS + threadIdx.x; p < kE; p += 256)
        atomicAdd(&cntS[ebufK[p] - nbase], 1);
    __syncthreads();
    for (int i = threadIdx.x; i < BNODES; i += 256) {
        int node = nbase + i;
        if (node < N) {
            cnt_dst[node] = cntD[i];
            rs_src[node] = rsqrtf((float)max(cntS[i], 1));
        }
    }
}

// ------------------------------------------------ partD2: per-bucket local scatter (LDS cursors)
__global__ __launch_bounds__(256) void partD2(const int* __restrict__ ebufS,
                                              const int* __restrict__ ebufD,
                                              const int* __restrict__ histJs,
                                              const int* __restrict__ offs,
                                              int* __restrict__ sortedSrc,
                                              int E, int G, int NB, int N) {
    __shared__ int cur[BNODES];
    int b = blockIdx.x;
    int nbase = b << BSHIFT;
    for (int i = threadIdx.x; i < BNODES; i += 256) {
        int node = nbase + i;
        cur[i] = (node < N) ? offs[node] : 0;
    }
    __syncthreads();
    int dS = histJs[b * G];
    int dE = (b + 1 < NB) ? histJs[(b + 1) * G] : E;
    for (int p = dS + threadIdx.x; p < dE; p += 256) {
        int d = ebufD[p];
        int s = ebufS[p];
        int pos = atomicAdd(&cur[d - nbase], 1);
        sortedSrc[pos] = s;
    }
}

// ------------------------------------------------ gather: S[i] = rs_dst[i] * sum rs_src[sj] * X[sj]
__global__ __launch_bounds__(256) void gather_kernel(
    const int* __restrict__ offs, const int* __restrict__ cnt_dst,
    const int* __restrict__ sortedSrc, const float* __restrict__ rs_src,
    const float* __restrict__ X, float* __restrict__ S, int n) {
    int lane = threadIdx.x & 63;
    int node = blockIdx.x * 4 + (threadIdx.x >> 6);
    if (node >= n) return;
    int start = offs[node];
    int cnt = cnt_dst[node];
    int end = start + cnt;
    float acc = 0.0f;
    int p = start;
    for (; p + 8 <= end; p += 8) {
        int idx[8];
        float w[8];
        float r[8];
#pragma unroll
        for (int j = 0; j < 8; ++j) idx[j] = sortedSrc[p + j];
#pragma unroll
        for (int j = 0; j < 8; ++j) w[j] = rs_src[idx[j]];
#pragma unroll
        for (int j = 0; j < 8; ++j) r[j] = X[(size_t)idx[j] * D + lane];
#pragma unroll
        for (int j = 0; j < 8; ++j) acc = fmaf(w[j], r[j], acc);
    }
    if (p < end) {  // clamped predicated tail: loads stay independent
        int idx[8];
        float w[8];
        float r[8];
#pragma unroll
        for (int j = 0; j < 8; ++j) {
            int q = p + j;
            int qc = (q < end) ? q : (end - 1);
            idx[j] = sortedSrc[qc];
        }
#pragma unroll
        for (int j = 0; j < 8; ++j) w[j] = (p + j < end) ? rs_src[idx[j]] : 0.0f;
#pragma unroll
        for (int j = 0; j < 8; ++j) r[j] = X[(size_t)idx[j] * D + lane];
#pragma unroll
        for (int j = 0; j < 8; ++j) acc = fmaf(w[j], r[j], acc);
    }
    float rd = rsqrtf((float)max(cnt, 1));
    S[(size_t)node * D + lane] = acc * rd;
}

// ------------------------------------------------ combine: Out = (X+S)@W1 + (X*S)@W2
// Thread-per-row FMA core kept from R7 (named float4 acc, VGPR-resident, clean
// 25MB write). NEW: X/S rows come through LDS, loaded COALESCED (thread =
// (rowgroup,quad): 4 consecutive threads = 64 contiguous bytes of one row; every
// HBM line fetched exactly once) — R7's strided per-thread float4 loads caused
// 134MB fetch vs 51MB demand. [256][17] padding -> 2-way LDS conflict (free).
// 4 phases x 16 k-cols; global loads issued before the barrier (overlap prev
// compute). Layer-2 X==Out alias safe: block reads only its own rows, all loads
// precede all stores, disjoint rows across blocks.
#define CK_COLS(Ai, i, u, v, wrow1, wrow2)                                \
    {                                                                     \
        float4 w1v = *(const float4*)((wrow1) + (i) * 4);                 \
        float4 w2v = *(const float4*)((wrow2) + (i) * 4);                 \
        Ai.x = fmaf(u, w1v.x, fmaf(v, w2v.x, Ai.x));                      \
        Ai.y = fmaf(u, w1v.y, fmaf(v, w2v.y, Ai.y));                      \
        Ai.z = fmaf(u, w1v.z, fmaf(v, w2v.z, Ai.z));                      \
        Ai.w = fmaf(u, w1v.w, fmaf(v, w2v.w, Ai.w));                      \
    }
#define CK_ALL16(u, v, wrow1, wrow2)                                      \
    CK_COLS(A0, 0, u, v, wrow1, wrow2)                                    \
    CK_COLS(A1, 1, u, v, wrow1, wrow2)                                    \
    CK_COLS(A2, 2, u, v, wrow1, wrow2)                                    \
    CK_COLS(A3, 3, u, v, wrow1, wrow2)                                    \
    CK_COLS(A4, 4, u, v, wrow1, wrow2)                                    \
    CK_COLS(A5, 5, u, v, wrow1, wrow2)                                    \
    CK_COLS(A6, 6, u, v, wrow1, wrow2)                                    \
    CK_COLS(A7, 7, u, v, wrow1, wrow2)                                    \
    CK_COLS(A8, 8, u, v, wrow1, wrow2)                                    \
    CK_COLS(A9, 9, u, v, wrow1, wrow2)                                    \
    CK_COLS(A10, 10, u, v, wrow1, wrow2)                                  \
    CK_COLS(A11, 11, u, v, wrow1, wrow2)                                  \
    CK_COLS(A12, 12, u, v, wrow1, wrow2)                                  \
    CK_COLS(A13, 13, u, v, wrow1, wrow2)                                  \
    CK_COLS(A14, 14, u, v, wrow1, wrow2)                                  \
    CK_COLS(A15, 15, u, v, wrow1, wrow2)
#define CK_RELU(Ai)                                                       \
    {                                                                     \
        Ai.x = fmaxf(Ai.x, 0.0f); Ai.y = fmaxf(Ai.y, 0.0f);               \
        Ai.z = fmaxf(Ai.z, 0.0f); Ai.w = fmaxf(Ai.w, 0.0f);               \
    }

__global__ __launch_bounds__(256, 2) void combine_kernel(
    const float* X, const float* S,
    const float* __restrict__ W1, const float* __restrict__ W2,
    float* Out, int n, int relu_flag) {
    __shared__ float xs[256][17];
    __shared__ float ss[256][17];
    int t = threadIdx.x;
    int rowBase = blockIdx.x * 256;
    int row0 = rowBase + t;
    int quad = t & 3;          // which float4 of the 16-col slice
    int lrow = t >> 2;         // 0..63: row within the 64-row load pass

    float4 A0 = make_float4(0.f, 0.f, 0.f, 0.f);
    float4 A1 = A0, A2 = A0, A3 = A0, A4 = A0, A5 = A0, A6 = A0, A7 = A0;
    float4 A8 = A0, A9 = A0, A10 = A0, A11 = A0, A12 = A0, A13 = A0, A14 = A0, A15 = A0;

#pragma unroll 1
    for (int ph = 0; ph < 4; ++ph) {
        int kbase = ph * 16;
        // coalesced global -> regs (issued before barrier: overlaps prev compute)
        float4 xv0, xv1, xv2, xv3, sv0, sv1, sv2, sv3;
        {
            int g0 = min(rowBase + 0 * 64 + lrow, n - 1);
            int g1 = min(rowBase + 1 * 64 + lrow, n - 1);
            int g2 = min(rowBase + 2 * 64 + lrow, n - 1);
            int g3 = min(rowBase + 3 * 64 + lrow, n - 1);
            const float* xb = X + kbase + quad * 4;
            const float* sb = S + kbase + quad * 4;
            xv0 = *(const float4*)(xb + (size_t)g0 * D);
            xv1 = *(const float4*)(xb + (size_t)g1 * D);
            xv2 = *(const float4*)(xb + (size_t)g2 * D);
            xv3 = *(const float4*)(xb + (size_t)g3 * D);
            sv0 = *(const float4*)(sb + (size_t)g0 * D);
            sv1 = *(const float4*)(sb + (size_t)g1 * D);
            sv2 = *(const float4*)(sb + (size_t)g2 * D);
            sv3 = *(const float4*)(sb + (size_t)g3 * D);
        }
        __syncthreads();   // previous phase's compute done reading LDS
        {
            int c = quad * 4;
            xs[0 * 64 + lrow][c + 0] = xv0.x; xs[0 * 64 + lrow][c + 1] = xv0.y;
            xs[0 * 64 + lrow][c + 2] = xv0.z; xs[0 * 64 + lrow][c + 3] = xv0.w;
            xs[1 * 64 + lrow][c + 0] = xv1.x; xs[1 * 64 + lrow][c + 1] = xv1.y;
            xs[1 * 64 + lrow][c + 2] = xv1.z; xs[1 * 64 + lrow][c + 3] = xv1.w;
            xs[2 * 64 + lrow][c + 0] = xv2.x; xs[2 * 64 + lrow][c + 1] = xv2.y;
            xs[2 * 64 + lrow][c + 2] = xv2.z; xs[2 * 64 + lrow][c + 3] = xv2.w;
            xs[3 * 64 + lrow][c + 0] = xv3.x; xs[3 * 64 + lrow][c + 1] = xv3.y;
            xs[3 * 64 + lrow][c + 2] = xv3.z; xs[3 * 64 + lrow][c + 3] = xv3.w;
            ss[0 * 64 + lrow][c + 0] = sv0.x; ss[0 * 64 + lrow][c + 1] = sv0.y;
            ss[0 * 64 + lrow][c + 2] = sv0.z; ss[0 * 64 + lrow][c + 3] = sv0.w;
            ss[1 * 64 + lrow][c + 0] = sv1.x; ss[1 * 64 + lrow][c + 1] = sv1.y;
            ss[1 * 64 + lrow][c + 2] = sv1.z; ss[1 * 64 + lrow][c + 3] = sv1.w;
            ss[2 * 64 + lrow][c + 0] = sv2.x; ss[2 * 64 + lrow][c + 1] = sv2.y;
            ss[2 * 64 + lrow][c + 2] = sv2.z; ss[2 * 64 + lrow][c + 3] = sv2.w;
            ss[3 * 64 + lrow][c + 0] = sv3.x; ss[3 * 64 + lrow][c + 1] = sv3.y;
            ss[3 * 64 + lrow][c + 2] = sv3.z; ss[3 * 64 + lrow][c + 3] = sv3.w;
        }
        __syncthreads();   // slice ready
#pragma unroll 4
        for (int j = 0; j < 16; ++j) {
            float xk = xs[t][j];
            float sk = ss[t][j];
            float u = xk + sk;
            float v = xk * sk;
            const float* w1k = W1 + (kbase + j) * D;   // uniform -> scalar base
            const float* w2k = W2 + (kbase + j) * D;
            CK_ALL16(u, v, w1k, w2k)
        }
    }

    if (row0 < n) {
        if (relu_flag) {
            CK_RELU(A0)  CK_RELU(A1)  CK_RELU(A2)  CK_RELU(A3)
            CK_RELU(A4)  CK_RELU(A5)  CK_RELU(A6)  CK_RELU(A7)
            CK_RELU(A8)  CK_RELU(A9)  CK_RELU(A10) CK_RELU(A11)
            CK_RELU(A12) CK_RELU(A13) CK_RELU(A14) CK_RELU(A15)
        }
        float4* o4 = (float4*)(Out + (size_t)row0 * D);
        o4[0] = A0;   o4[1] = A1;   o4[2] = A2;   o4[3] = A3;
        o4[4] = A4;   o4[5] = A5;   o4[6] = A6;   o4[7] = A7;
        o4[8] = A8;   o4[9] = A9;   o4[10] = A10; o4[11] = A11;
        o4[12] = A12; o4[13] = A13; o4[14] = A14; o4[15] = A15;
    }
}

extern "C" void kernel_launch(void* const* d_in, const int* in_sizes, int n_in,
                              void* d_out, int out_size, void* d_ws, size_t ws_size,
                              hipStream_t stream) {
    const float* x    = (const float*)d_in[0];
    const int*   src  = (const int*)d_in[1];
    const int*   dst  = (const int*)d_in[2];
    const float* W1_1 = (const float*)d_in[3];
    const float* W2_1 = (const float*)d_in[4];
    const float* W1_2 = (const float*)d_in[5];
    const float* W2_2 = (const float*)d_in[6];
    float* out = (float*)d_out;

    const int N = in_sizes[0] / D;
    const int E = in_sizes[1];

    const int NB = (N + BNODES - 1) >> BSHIFT;     // node buckets (196 for N=100000)
    const int G  = (E + CHUNK - 1) / CHUNK;        // partition chunks (196)
    const int HL = NB * G;

    // ws layout (4B units):
    // cnt_dst[N] | offs[N] | rs_src[N] | sortedSrc[E] | histJ[2HL] | histJs[2HL] | S[N*D]
    // ebufS/ebufD/ebufK alias S (19.2MB < 25.6MB; all dead before gather writes S).
    int*   cnt_dst   = (int*)d_ws;
    int*   offs      = cnt_dst + N;
    float* rs_src    = (float*)(cnt_dst + 2 * (size_t)N);
    int*   sortedSrc = cnt_dst + 3 * (size_t)N;
    int*   histJ     = sortedSrc + E;
    int*   histJs    = histJ + 2 * (size_t)HL;
    float* S         = (float*)(histJs + 2 * (size_t)HL);
    int*   ebufS     = (int*)S;
    int*   ebufD     = ebufS + E;
    int*   ebufK     = ebufD + E;

    const int tb = 256;
    const int n_blocks = (N + tb - 1) / tb;
    const int g_blocks = (N + 3) / 4;
    const int nchunksN = (N + SCAN_CHUNK - 1) / SCAN_CHUNK;
    const int nchunksJ = (2 * HL + SCAN_CHUNK - 1) / SCAN_CHUNK;

    // ---- joint bucket histograms (dst + src) and joint scan
    partAB<<<G, tb, 0, stream>>>(src, dst, histJ, E, G, NB, HL);
    scanA<<<nchunksJ, tb, 0, stream>>>(histJ, 2 * HL);
    scanB<<<1, 128, 0, stream>>>(nchunksJ);
    scanC<<<nchunksJ, tb, 0, stream>>>(histJ, histJs, 2 * HL);

    // ---- bucket-major reorder for both partitions
    partCJ<<<G, tb, 0, stream>>>(src, dst, histJs, ebufS, ebufD, ebufK, E, G, NB, HL);

    // ---- per-node degrees (coalesced, no global atomics) + rs_src
    partDcount<<<NB, tb, 0, stream>>>(ebufD, ebufK, histJs, cnt_dst, rs_src, E, G, NB, HL, N);

    // ---- offs = exclusive scan of cnt_dst
    scanA<<<nchunksN, tb, 0, stream>>>(cnt_dst, N);
    scanB<<<1, 128, 0, stream>>>(nchunksN);
    scanC<<<nchunksN, tb, 0, stream>>>(cnt_dst, offs, N);

    // ---- CSR scatter
    partD2<<<NB, tb, 0, stream>>>(ebufS, ebufD, histJs, offs, sortedSrc, E, G, NB, N);

    // ---- layer 1: h = relu((x+S)@W1_1 + (x*S)@W2_1), h lives in d_out
    gather_kernel<<<g_blocks, tb, 0, stream>>>(offs, cnt_dst, sortedSrc, rs_src, x, S, N);
    combine_kernel<<<n_blocks, tb, 0, stream>>>(x, S, W1_1, W2_1, out, N, 1);

    // ---- layer 2: out = (h+S)@W1_2 + (h*S)@W2_2
    gather_kernel<<<g_blocks, tb, 0, stream>>>(offs, cnt_dst, sortedSrc, rs_src, out, S, N);
    combine_kernel<<<n_blocks, tb, 0, stream>>>(out, S, W1_2, W2_2, out, N, 0);
}

// Round 10
// 368.078 us; speedup vs baseline: 1.2182x; 1.2182x over previous
//
#include <hip/hip_runtime.h>

#define D 64
#define SCAN_CHUNK 1024
#define MAX_CHUNKS 128
#define BSHIFT 9                 // 512 nodes per bucket
#define BNODES (1 << BSHIFT)
#define CHUNK 8192               // edges per partition block

__device__ int g_partials[MAX_CHUNKS];

// ------------------------------------------------ exclusive scan (3 kernels)
__global__ __launch_bounds__(256) void scanA(const int* __restrict__ cnt, int n) {
    __shared__ int red[256];
    int b = blockIdx.x, t = threadIdx.x;
    int base = b * SCAN_CHUNK + t * 4;
    int s = 0;
#pragma unroll
    for (int j = 0; j < 4; ++j) {
        int i = base + j;
        if (i < n) s += cnt[i];
    }
    red[t] = s;
    __syncthreads();
    for (int off = 128; off > 0; off >>= 1) {
        if (t < off) red[t] += red[t + off];
        __syncthreads();
    }
    if (t == 0) g_partials[b] = red[0];
}

__global__ __launch_bounds__(128) void scanB(int nchunks) {
    __shared__ int sh[MAX_CHUNKS];
    int t = threadIdx.x;
    int v = (t < nchunks) ? g_partials[t] : 0;
    sh[t] = v;
    __syncthreads();
    for (int off = 1; off < MAX_CHUNKS; off <<= 1) {
        int a = (t >= off) ? sh[t - off] : 0;
        __syncthreads();
        sh[t] += a;
        __syncthreads();
    }
    if (t < nchunks) g_partials[t] = sh[t] - v;  // exclusive
}

// out-of-place: offs[i] = exclusive_prefix(cnt)[i]  (cnt preserved)
__global__ __launch_bounds__(256) void scanC(const int* __restrict__ cnt,
                                             int* __restrict__ offs, int n) {
    __shared__ int sums[256];
    int b = blockIdx.x, t = threadIdx.x;
    int base = b * SCAN_CHUNK + t * 4;
    int v[4];
    int tot = 0;
#pragma unroll
    for (int j = 0; j < 4; ++j) {
        int i = base + j;
        v[j] = (i < n) ? cnt[i] : 0;
        tot += v[j];
    }
    sums[t] = tot;
    __syncthreads();
    for (int off = 1; off < 256; off <<= 1) {
        int a = (t >= off) ? sums[t - off] : 0;
        __syncthreads();
        sums[t] += a;
        __syncthreads();
    }
    int run = sums[t] - tot + g_partials[b];
#pragma unroll
    for (int j = 0; j < 4; ++j) {
        int i = base + j;
        if (i < n) offs[i] = run;
        run += v[j];
    }
}

// ------------------------------------------------ partAB: per-(chunk,bucket) counts for dst AND src
__global__ __launch_bounds__(256) void partAB(const int* __restrict__ src,
                                              const int* __restrict__ dst,
                                              int* __restrict__ histJ,
                                              int E, int G, int NB, int HL) {
    __shared__ int hD[256], hS[256];
    int g = blockIdx.x;
    hD[threadIdx.x] = 0;
    hS[threadIdx.x] = 0;
    __syncthreads();
    int base = g * CHUNK;
    int lim = min(E - base, CHUNK);
    for (int i = threadIdx.x; i < lim; i += 256) {
        atomicAdd(&hD[dst[base + i] >> BSHIFT], 1);
        atomicAdd(&hS[src[base + i] >> BSHIFT], 1);
    }
    __syncthreads();
    if (threadIdx.x < NB) {
        histJ[threadIdx.x * G + g] = hD[threadIdx.x];
        histJ[HL + threadIdx.x * G + g] = hS[threadIdx.x];
    }
}

// ------------------------------------------------ partCJ: bucket-major reorder for both partitions (SoA)
__global__ __launch_bounds__(256) void partCJ(const int* __restrict__ src,
                                              const int* __restrict__ dst,
                                              const int* __restrict__ histJs,
                                              int* __restrict__ ebufS, int* __restrict__ ebufD,
                                              int* __restrict__ ebufK,
                                              int E, int G, int NB, int HL) {
    __shared__ int curD[256], curK[256];
    int g = blockIdx.x;
    if (threadIdx.x < NB) {
        curD[threadIdx.x] = histJs[threadIdx.x * G + g];
        curK[threadIdx.x] = histJs[HL + threadIdx.x * G + g];
    }
    __syncthreads();
    int base = g * CHUNK;
    int lim = min(E - base, CHUNK);
    for (int i = threadIdx.x; i < lim; i += 256) {
        int d = dst[base + i];
        int s = src[base + i];
        int pD = atomicAdd(&curD[d >> BSHIFT], 1);
        ebufS[pD] = s;
        ebufD[pD] = d;
        int pK = atomicAdd(&curK[s >> BSHIFT], 1) - E;  // src positions offset by E in joint scan
        ebufK[pK] = s;
    }
}

// ------------------------------------------------ partDcount: per-bucket node degrees (LDS), coalesced writes
__global__ __launch_bounds__(256) void partDcount(const int* __restrict__ ebufD,
                                                  const int* __restrict__ ebufK,
                                                  const int* __restrict__ histJs,
                                                  int* __restrict__ cnt_dst, float* __restrict__ rs_src,
                                                  int E, int G, int NB, int HL, int N) {
    __shared__ int cntD[BNODES], cntS[BNODES];
    int b = blockIdx.x;
    int nbase = b << BSHIFT;
    for (int i = threadIdx.x; i < BNODES; i += 256) { cntD[i] = 0; cntS[i] = 0; }
    __syncthreads();
    int dS = histJs[b * G];
    int dE = (b + 1 < NB) ? histJs[(b + 1) * G] : E;
    for (int p = dS + threadIdx.x; p < dE; p += 256)
        atomicAdd(&cntD[ebufD[p] - nbase], 1);
    int kS = histJs[HL + b * G] - E;
    int kE = (b + 1 < NB) ? histJs[HL + (b + 1) * G] - E : E;
    for (int p = kS + threadIdx.x; p < kE; p += 256)
        atomicAdd(&cntS[ebufK[p] - nbase], 1);
    __syncthreads();
    for (int i = threadIdx.x; i < BNODES; i += 256) {
        int node = nbase + i;
        if (node < N) {
            cnt_dst[node] = cntD[i];
            rs_src[node] = rsqrtf((float)max(cntS[i], 1));
        }
    }
}

// ------------------------------------------------ partD2: per-bucket local scatter (LDS cursors)
__global__ __launch_bounds__(256) void partD2(const int* __restrict__ ebufS,
                                              const int* __restrict__ ebufD,
                                              const int* __restrict__ histJs,
                                              const int* __restrict__ offs,
                                              int* __restrict__ sortedSrc,
                                              int E, int G, int NB, int N) {
    __shared__ int cur[BNODES];
    int b = blockIdx.x;
    int nbase = b << BSHIFT;
    for (int i = threadIdx.x; i < BNODES; i += 256) {
        int node = nbase + i;
        cur[i] = (node < N) ? offs[node] : 0;
    }
    __syncthreads();
    int dS = histJs[b * G];
    int dE = (b + 1 < NB) ? histJs[(b + 1) * G] : E;
    for (int p = dS + threadIdx.x; p < dE; p += 256) {
        int d = ebufD[p];
        int s = ebufS[p];
        int pos = atomicAdd(&cur[d - nbase], 1);
        sortedSrc[pos] = s;
    }
}

// ------------------------------------------------ gather: S[i] = rs_dst[i] * sum rs_src[sj] * X[sj]
__global__ __launch_bounds__(256) void gather_kernel(
    const int* __restrict__ offs, const int* __restrict__ cnt_dst,
    const int* __restrict__ sortedSrc, const float* __restrict__ rs_src,
    const float* __restrict__ X, float* __restrict__ S, int n) {
    int lane = threadIdx.x & 63;
    int node = blockIdx.x * 4 + (threadIdx.x >> 6);
    if (node >= n) return;
    int start = offs[node];
    int cnt = cnt_dst[node];
    int end = start + cnt;
    float acc = 0.0f;
    int p = start;
    for (; p + 8 <= end; p += 8) {
        int idx[8];
        float w[8];
        float r[8];
#pragma unroll
        for (int j = 0; j < 8; ++j) idx[j] = sortedSrc[p + j];
#pragma unroll
        for (int j = 0; j < 8; ++j) w[j] = rs_src[idx[j]];
#pragma unroll
        for (int j = 0; j < 8; ++j) r[j] = X[(size_t)idx[j] * D + lane];
#pragma unroll
        for (int j = 0; j < 8; ++j) acc = fmaf(w[j], r[j], acc);
    }
    if (p < end) {  // clamped predicated tail: loads stay independent
        int idx[8];
        float w[8];
        float r[8];
#pragma unroll
        for (int j = 0; j < 8; ++j) {
            int q = p + j;
            int qc = (q < end) ? q : (end - 1);
            idx[j] = sortedSrc[qc];
        }
#pragma unroll
        for (int j = 0; j < 8; ++j) w[j] = (p + j < end) ? rs_src[idx[j]] : 0.0f;
#pragma unroll
        for (int j = 0; j < 8; ++j) r[j] = X[(size_t)idx[j] * D + lane];
#pragma unroll
        for (int j = 0; j < 8; ++j) acc = fmaf(w[j], r[j], acc);
    }
    float rd = rsqrtf((float)max(cnt, 1));
    S[(size_t)node * D + lane] = acc * rd;
}

// ------------------------------------------------ combine: Out = (X+S)@W1 + (X*S)@W2
// R9: latency-bound fix (R8: 391 blocks = 1.5/CU, Occ 15%). Block = 64 rows,
// grid 1563 (~4 blocks/CU after 33KB LDS cap -> ~50% occ). Stage full 64x64
// x/s tile once (coalesced, [64][65] pad -> 2-way = free), ONE barrier, then
// wave w computes cols [16w,16w+16) for all 64 rows: 4 named float4 acc,
// W uniform via readfirstlane(wv) -> s_load, LDS read (lane+j)%32 2-way free.
// Each lane stores one full 64B line (no RMW). #pragma unroll 2 (R5 lesson).
// Layer-2 X==Out alias safe: block reads only rows [rowBase,rowBase+64), all
// reads precede its stores; clamp row stays within the last block's own range.
__global__ __launch_bounds__(256, 4) void combine_kernel(
    const float* X, const float* S,
    const float* __restrict__ W1, const float* __restrict__ W2,
    float* Out, int n, int relu_flag) {
    __shared__ float xs[64][65];
    __shared__ float ss[64][65];
    int t = threadIdx.x;
    int rowBase = blockIdx.x * 64;
    int lane = t & 63;
    int wv = __builtin_amdgcn_readfirstlane(t >> 6);   // wave id -> uniform col slice
    int q = t & 15;            // staging: quad (16 quads = 64 cols)
    int sr = t >> 4;           // staging: row 0..15 per pass

    // ---- stage 64 rows x 64 cols of X and S (coalesced: 4 consecutive threads
    // cover 64 contiguous bytes; every HBM line touched exactly once)
#pragma unroll
    for (int p = 0; p < 4; ++p) {
        int r = p * 16 + sr;
        int g = min(rowBase + r, n - 1);
        float4 xv = *(const float4*)(X + (size_t)g * D + q * 4);
        float4 sv = *(const float4*)(S + (size_t)g * D + q * 4);
        int c = q * 4;
        xs[r][c + 0] = xv.x; xs[r][c + 1] = xv.y;
        xs[r][c + 2] = xv.z; xs[r][c + 3] = xv.w;
        ss[r][c + 0] = sv.x; ss[r][c + 1] = sv.y;
        ss[r][c + 2] = sv.z; ss[r][c + 3] = sv.w;
    }
    __syncthreads();

    // ---- compute: wave wv -> cols [wv*16, wv*16+16), row = lane
    float4 A0 = make_float4(0.f, 0.f, 0.f, 0.f);
    float4 A1 = A0, A2 = A0, A3 = A0;
    const float* W1c = W1 + wv * 16;   // uniform -> scalar base
    const float* W2c = W2 + wv * 16;
#pragma unroll 2
    for (int j = 0; j < 64; ++j) {
        float xk = xs[lane][j];
        float sk = ss[lane][j];
        float u = xk + sk;
        float v = xk * sk;
        float4 w10 = *(const float4*)(W1c + j * D + 0);
        float4 w11 = *(const float4*)(W1c + j * D + 4);
        float4 w12 = *(const float4*)(W1c + j * D + 8);
        float4 w13 = *(const float4*)(W1c + j * D + 12);
        float4 w20 = *(const float4*)(W2c + j * D + 0);
        float4 w21 = *(const float4*)(W2c + j * D + 4);
        float4 w22 = *(const float4*)(W2c + j * D + 8);
        float4 w23 = *(const float4*)(W2c + j * D + 12);
        A0.x = fmaf(u, w10.x, fmaf(v, w20.x, A0.x));
        A0.y = fmaf(u, w10.y, fmaf(v, w20.y, A0.y));
        A0.z = fmaf(u, w10.z, fmaf(v, w20.z, A0.z));
        A0.w = fmaf(u, w10.w, fmaf(v, w20.w, A0.w));
        A1.x = fmaf(u, w11.x, fmaf(v, w21.x, A1.x));
        A1.y = fmaf(u, w11.y, fmaf(v, w21.y, A1.y));
        A1.z = fmaf(u, w11.z, fmaf(v, w21.z, A1.z));
        A1.w = fmaf(u, w11.w, fmaf(v, w21.w, A1.w));
        A2.x = fmaf(u, w12.x, fmaf(v, w22.x, A2.x));
        A2.y = fmaf(u, w12.y, fmaf(v, w22.y, A2.y));
        A2.z = fmaf(u, w12.z, fmaf(v, w22.z, A2.z));
        A2.w = fmaf(u, w12.w, fmaf(v, w22.w, A2.w));
        A3.x = fmaf(u, w13.x, fmaf(v, w23.x, A3.x));
        A3.y = fmaf(u, w13.y, fmaf(v, w23.y, A3.y));
        A3.z = fmaf(u, w13.z, fmaf(v, w23.z, A3.z));
        A3.w = fmaf(u, w13.w, fmaf(v, w23.w, A3.w));
    }

    int row0 = rowBase + lane;
    if (row0 < n) {
        if (relu_flag) {
            A0.x = fmaxf(A0.x, 0.f); A0.y = fmaxf(A0.y, 0.f);
            A0.z = fmaxf(A0.z, 0.f); A0.w = fmaxf(A0.w, 0.f);
            A1.x = fmaxf(A1.x, 0.f); A1.y = fmaxf(A1.y, 0.f);
            A1.z = fmaxf(A1.z, 0.f); A1.w = fmaxf(A1.w, 0.f);
            A2.x = fmaxf(A2.x, 0.f); A2.y = fmaxf(A2.y, 0.f);
            A2.z = fmaxf(A2.z, 0.f); A2.w = fmaxf(A2.w, 0.f);
            A3.x = fmaxf(A3.x, 0.f); A3.y = fmaxf(A3.y, 0.f);
            A3.z = fmaxf(A3.z, 0.f); A3.w = fmaxf(A3.w, 0.f);
        }
        float4* o4 = (float4*)(Out + (size_t)row0 * D + wv * 16);
        o4[0] = A0; o4[1] = A1; o4[2] = A2; o4[3] = A3;
    }
}

extern "C" void kernel_launch(void* const* d_in, const int* in_sizes, int n_in,
                              void* d_out, int out_size, void* d_ws, size_t ws_size,
                              hipStream_t stream) {
    const float* x    = (const float*)d_in[0];
    const int*   src  = (const int*)d_in[1];
    const int*   dst  = (const int*)d_in[2];
    const float* W1_1 = (const float*)d_in[3];
    const float* W2_1 = (const float*)d_in[4];
    const float* W1_2 = (const float*)d_in[5];
    const float* W2_2 = (const float*)d_in[6];
    float* out = (float*)d_out;

    const int N = in_sizes[0] / D;
    const int E = in_sizes[1];

    const int NB = (N + BNODES - 1) >> BSHIFT;     // node buckets (196 for N=100000)
    const int G  = (E + CHUNK - 1) / CHUNK;        // partition chunks (196)
    const int HL = NB * G;

    // ws layout (4B units):
    // cnt_dst[N] | offs[N] | rs_src[N] | sortedSrc[E] | histJ[2HL] | histJs[2HL] | S[N*D]
    // ebufS/ebufD/ebufK alias S (19.2MB < 25.6MB; all dead before gather writes S).
    int*   cnt_dst   = (int*)d_ws;
    int*   offs      = cnt_dst + N;
    float* rs_src    = (float*)(cnt_dst + 2 * (size_t)N);
    int*   sortedSrc = cnt_dst + 3 * (size_t)N;
    int*   histJ     = sortedSrc + E;
    int*   histJs    = histJ + 2 * (size_t)HL;
    float* S         = (float*)(histJs + 2 * (size_t)HL);
    int*   ebufS     = (int*)S;
    int*   ebufD     = ebufS + E;
    int*   ebufK     = ebufD + E;

    const int tb = 256;
    const int g_blocks = (N + 3) / 4;
    const int c_blocks = (N + 63) / 64;
    const int nchunksN = (N + SCAN_CHUNK - 1) / SCAN_CHUNK;
    const int nchunksJ = (2 * HL + SCAN_CHUNK - 1) / SCAN_CHUNK;

    // ---- joint bucket histograms (dst + src) and joint scan
    partAB<<<G, tb, 0, stream>>>(src, dst, histJ, E, G, NB, HL);
    scanA<<<nchunksJ, tb, 0, stream>>>(histJ, 2 * HL);
    scanB<<<1, 128, 0, stream>>>(nchunksJ);
    scanC<<<nchunksJ, tb, 0, stream>>>(histJ, histJs, 2 * HL);

    // ---- bucket-major reorder for both partitions
    partCJ<<<G, tb, 0, stream>>>(src, dst, histJs, ebufS, ebufD, ebufK, E, G, NB, HL);

    // ---- per-node degrees (coalesced, no global atomics) + rs_src
    partDcount<<<NB, tb, 0, stream>>>(ebufD, ebufK, histJs, cnt_dst, rs_src, E, G, NB, HL, N);

    // ---- offs = exclusive scan of cnt_dst
    scanA<<<nchunksN, tb, 0, stream>>>(cnt_dst, N);
    scanB<<<1, 128, 0, stream>>>(nchunksN);
    scanC<<<nchunksN, tb, 0, stream>>>(cnt_dst, offs, N);

    // ---- CSR scatter
    partD2<<<NB, tb, 0, stream>>>(ebufS, ebufD, histJs, offs, sortedSrc, E, G, NB, N);

    // ---- layer 1: h = relu((x+S)@W1_1 + (x*S)@W2_1), h lives in d_out
    gather_kernel<<<g_blocks, tb, 0, stream>>>(offs, cnt_dst, sortedSrc, rs_src, x, S, N);
    combine_kernel<<<c_blocks, tb, 0, stream>>>(x, S, W1_1, W2_1, out, N, 1);

    // ---- layer 2: out = (h+S)@W1_2 + (h*S)@W2_2
    gather_kernel<<<g_blocks, tb, 0, stream>>>(offs, cnt_dst, sortedSrc, rs_src, out, S, N);
    combine_kernel<<<c_blocks, tb, 0, stream>>>(out, S, W1_2, W2_2, out, N, 0);
}